// Round 4
// baseline (489.177 us; speedup 1.0000x reference)
//
#include <hip/hip_runtime.h>
#include <hip/hip_bf16.h>
#include <stdint.h>

#define EPSF 1e-5f

typedef __attribute__((ext_vector_type(4))) int i32x4;
typedef __attribute__((ext_vector_type(16))) int i32x16;
typedef __attribute__((ext_vector_type(16))) char c8x16;

__device__ __forceinline__ void gld_lds16(const void* g, void* l) {
  __builtin_amdgcn_global_load_lds((const __attribute__((address_space(1))) void*)g,
                                   (__attribute__((address_space(3))) void*)l, 16, 0, 0);
}

// ---------------- prep: binarize weights [1024 x Ksrc] f32 -> i8 [1024][1024], zero-pad ----------------
__global__ void k_binW(const float* __restrict__ src, char* __restrict__ dst, int Ksrc) {
  int t = blockIdx.x * 256 + threadIdx.x;  // 65536 threads, 16 i8 each
  int c = t & 63;
  int n = t >> 6;
  int kc = Ksrc >> 4;  // 49 (784) or 64 (1024)
  c8x16 o;
  if (c < kc) {
    const float* p = src + (size_t)n * Ksrc + c * 16;
#pragma unroll
    for (int e = 0; e < 16; ++e) o[e] = (p[e] >= 0.0f) ? (char)1 : (char)-1;
  } else {
    o = (c8x16)0;
  }
  *(c8x16*)(dst + (size_t)t * 16) = o;
}

// ---------------- input binarize: x [65536 x 784] f32 -> X [65536 x 1024] i8 +-1, pad 0 ----------------
// sign(2x-1) == (x >= 0.5) exactly
__global__ void k_binX(const float* __restrict__ x, char* __restrict__ X) {
  size_t t = (size_t)blockIdx.x * 256 + threadIdx.x;  // 65536*64 threads
  int c = (int)(t & 63);
  size_t b = t >> 6;
  c8x16 o;
  if (c < 49) {  // 784 = 49*16
    const float* p = x + b * 784 + c * 16;
#pragma unroll
    for (int e = 0; e < 16; ++e) o[e] = (p[e] >= 0.5f) ? (char)1 : (char)-1;
  } else {
    o = (c8x16)0;
  }
  *(c8x16*)(X + b * 1024 + c * 16) = o;
}

// ---------------- small prep: inv_std (exact numpy f32 rounding) + binarized WL [16][1024] i8 ----------------
__global__ void k_prep(const float* __restrict__ bn_gamma, const float* __restrict__ bn_var,
                       const float* __restrict__ bnL_gamma, const float* __restrict__ bnL_var,
                       const float* __restrict__ WL,
                       float* __restrict__ invstd3, float* __restrict__ invstdL,
                       char* __restrict__ WLb) {
  int j = threadIdx.x;  // 1024
#pragma unroll
  for (int i = 0; i < 3; ++i) {
    int idx = i * 1024 + j;
    invstd3[idx] = __fdiv_rn(bn_gamma[idx], __fsqrt_rn(__fadd_rn(bn_var[idx], EPSF)));
  }
  if (j < 10) invstdL[j] = __fdiv_rn(bnL_gamma[j], __fsqrt_rn(__fadd_rn(bnL_var[j], EPSF)));
#pragma unroll
  for (int r = 0; r < 16; ++r) {
    char v = 0;
    if (r < 10) v = (WL[r * 1024 + j] >= 0.0f) ? (char)1 : (char)-1;
    WLb[r * 1024 + j] = v;
  }
}

// ---------------- main fused GEMM: C_bin = binarize(BN(A @ Bt^T)), i8 +-1, 32x32x32 MFMA ----------------
// 128x128 tile, BK=64, 4 waves (2x2), each wave 2x2 of 32x32 tiles, 8 MFMA/K-tile/wave.
// LDS quarter-major [4][128][16B] per operand (linear in tid*16 for global_load_lds;
// ds_read_b128 is 32-lane-sequential -> conflict-free, no swizzle needed).
// T3-minimal 2-phase pipeline: double-buffered LDS, stage t+1 before compute t,
// one vmcnt(0)+s_barrier per K-tile (asm clobber precedes every barrier).
// XCD mapping: all 8 bn-blocks of one bm land on the same XCD.
__global__ __launch_bounds__(256, 3)
void gemm_bin(const char* __restrict__ A, const char* __restrict__ Bt,
              char* __restrict__ Cb,
              const float* __restrict__ mean, const float* __restrict__ beta,
              const float* __restrict__ invstd) {
  __shared__ char lds[32768];  // buf b at b*16384: sA [0,8192) quarters q*2048, sB [8192,16384)
  const int tid = threadIdx.x;
  const int lane = tid & 63;
  const int wave = tid >> 6;
  const int d = blockIdx.x;  // 0..4095
  const int xcd = d & 7;
  const int idx = d >> 3;
  const int bm = xcd * 64 + (idx >> 3);
  const int bn = idx & 7;
  const int wm = wave >> 1, wn = wave & 1;
  const int h = lane >> 5, r31 = lane & 31;

  // staging: thread t -> (q = t>>7, row = t&127), LDS linear offset t*16; round 1 -> q+2 (+4096)
  const int srow = tid & 127, sq = tid >> 7;
  const char* gAp = A + (size_t)(bm * 128 + srow) * 1024 + sq * 16;
  const char* gBp = Bt + (size_t)(bn * 128 + srow) * 1024 + sq * 16;
  const int lwoff = (tid & ~63) * 16;  // wave-uniform; HW adds lane*16

  // fragment offsets: k-step s, half h -> quarter q=2s+h at q*2048; row*16 within quarter
  const int aro = (wm * 64 + r31) * 16 + h * 2048;          // +512 for mt=1 (32 rows)
  const int bro = (wn * 64 + r31) * 16 + h * 2048 + 8192;   // +512 for nt=1

  i32x16 acc00 = (i32x16)0, acc01 = (i32x16)0, acc10 = (i32x16)0, acc11 = (i32x16)0;

  // prologue: stage tile 0 into buf0
  {
    char* lw = lds + lwoff;
    gld_lds16(gAp, lw);
    gld_lds16(gAp + 32, lw + 4096);
    gld_lds16(gBp, lw + 8192);
    gld_lds16(gBp + 32, lw + 12288);
    gAp += 64;
    gBp += 64;
  }
  asm volatile("s_waitcnt vmcnt(0)" ::: "memory");
  __builtin_amdgcn_sched_barrier(0);
  __builtin_amdgcn_s_barrier();

  for (int t = 0; t < 16; ++t) {
    const int cbase = (t & 1) << 14;
    if (t < 15) {  // stage next tile into the other buffer
      char* lw = lds + (cbase ^ 16384) + lwoff;
      gld_lds16(gAp, lw);
      gld_lds16(gAp + 32, lw + 4096);
      gld_lds16(gBp, lw + 8192);
      gld_lds16(gBp + 32, lw + 12288);
      gAp += 64;
      gBp += 64;
    }
    __builtin_amdgcn_s_setprio(1);
#pragma unroll
    for (int s = 0; s < 2; ++s) {
      const int qb = cbase + s * 4096;
      i32x4 a0 = *(const i32x4*)(lds + qb + aro);
      i32x4 a1 = *(const i32x4*)(lds + qb + aro + 512);
      i32x4 b0 = *(const i32x4*)(lds + qb + bro);
      i32x4 b1 = *(const i32x4*)(lds + qb + bro + 512);
      acc00 = __builtin_amdgcn_mfma_i32_32x32x32_i8(a0, b0, acc00, 0, 0, 0);
      acc01 = __builtin_amdgcn_mfma_i32_32x32x32_i8(a0, b1, acc01, 0, 0, 0);
      acc10 = __builtin_amdgcn_mfma_i32_32x32x32_i8(a1, b0, acc10, 0, 0, 0);
      acc11 = __builtin_amdgcn_mfma_i32_32x32x32_i8(a1, b1, acc11, 0, 0, 0);
    }
    __builtin_amdgcn_s_setprio(0);
    if (t < 15) {
      asm volatile("s_waitcnt vmcnt(0)" ::: "memory");  // next-tile stores landed
      __builtin_amdgcn_sched_barrier(0);
      __builtin_amdgcn_s_barrier();
    }
  }

  // epilogue: exact int -> f32, BN with np-f32 rounding (no FMA), binarize to i8
  // C/D 32x32 map: col = lane&31, row = (r&3) + 8*(r>>2) + 4*(lane>>5)
  const int rbase = bm * 128 + wm * 64 + 4 * h;
  const int cb0 = bn * 128 + wn * 64 + r31;
#pragma unroll
  for (int nt = 0; nt < 2; ++nt) {
    const int col = cb0 + nt * 32;
    const float mu = mean[col], is = invstd[col], be = beta[col];
#pragma unroll
    for (int mt = 0; mt < 2; ++mt) {
      const i32x16 a = (nt == 0) ? (mt == 0 ? acc00 : acc10) : (mt == 0 ? acc01 : acc11);
#pragma unroll
      for (int r = 0; r < 16; ++r) {
        const int row = rbase + mt * 32 + (r & 3) + 8 * (r >> 2);
        float y = __fadd_rn(__fmul_rn(__fsub_rn((float)a[r], mu), is), be);
        Cb[(size_t)row * 1024 + col] = (y >= 0.0f) ? (char)1 : (char)-1;
      }
    }
  }
}

// ---------------- final layer: out[65536][10] = BN(A @ WLb^T), fp32 out, i8 inputs ----------------
// (verified in R2 -- unchanged)
__global__ __launch_bounds__(256, 2)
void gemm_fin(const char* __restrict__ A, const char* __restrict__ BtL,
              float* __restrict__ out,
              const float* __restrict__ meanL, const float* __restrict__ betaL,
              const float* __restrict__ invstdL) {
  constexpr int K = 1024;
  __shared__ char sA[128 * 64];
  __shared__ char sB[16 * 64];
  const int tid = threadIdx.x;
  const int lane = tid & 63;
  const int wave = tid >> 6;
  const int bm = blockIdx.x;

  const int sr = tid >> 2;
  const int csrc = ((tid & 3) ^ (sr & 3)) << 4;
  const char* gA = A + (size_t)(bm * 128 + sr) * K + csrc;
  const char* gB = BtL + (size_t)sr * K + csrc;
  char* lA = sA + (tid & ~63) * 16;
  char* lB = sB;

  const int slot = ((lane >> 4) ^ (lane & 3)) << 4;
  const char* rA = sA + (wave * 32 + (lane & 15)) * 64 + slot;
  const char* rB = sB + (lane & 15) * 64 + slot;

  i32x4 acc0 = (i32x4)0, acc1 = (i32x4)0;

  for (int k0 = 0; k0 < K; k0 += 64) {
    gld_lds16(gA, lA);
    gld_lds16(gA + (size_t)64 * K, lA + 4096);
    if (tid < 64) gld_lds16(gB, lB);
    gA += 64;
    gB += 64;
    __syncthreads();
    i32x4 af0 = *(const i32x4*)(rA);
    i32x4 af1 = *(const i32x4*)(rA + 16 * 64);
    i32x4 b0 = *(const i32x4*)(rB);
    acc0 = __builtin_amdgcn_mfma_i32_16x16x64_i8(af0, b0, acc0, 0, 0, 0);
    acc1 = __builtin_amdgcn_mfma_i32_16x16x64_i8(af1, b0, acc1, 0, 0, 0);
    __syncthreads();
  }

  const int col = lane & 15;
  if (col < 10) {
    const float mu = meanL[col], is = invstdL[col], be = betaL[col];
    const int r0 = bm * 128 + wave * 32 + ((lane >> 4) << 2);
#pragma unroll
    for (int m = 0; m < 2; ++m) {
      const i32x4 a = (m == 0) ? acc0 : acc1;
#pragma unroll
      for (int j = 0; j < 4; ++j) {
        const int row = r0 + m * 16 + j;
        out[(size_t)row * 10 + col] = __fadd_rn(__fmul_rn(__fsub_rn((float)a[j], mu), is), be);
      }
    }
  }
}

extern "C" void kernel_launch(void* const* d_in, const int* in_sizes, int n_in,
                              void* d_out, int out_size, void* d_ws, size_t ws_size,
                              hipStream_t stream) {
  const float* x = (const float*)d_in[0];
  const float* W0 = (const float*)d_in[1];
  const float* Wh = (const float*)d_in[2];
  const float* WL = (const float*)d_in[3];
  const float* bn_gamma = (const float*)d_in[4];
  const float* bn_beta = (const float*)d_in[5];
  const float* bn_mean = (const float*)d_in[6];
  const float* bn_var = (const float*)d_in[7];
  const float* bnL_gamma = (const float*)d_in[8];
  const float* bnL_beta = (const float*)d_in[9];
  const float* bnL_mean = (const float*)d_in[10];
  const float* bnL_var = (const float*)d_in[11];
  float* out = (float*)d_out;

  // workspace layout (~140 MB)
  char* ws = (char*)d_ws;
  char* X0 = ws;                                   // 67108864 B
  char* X1 = ws + 67108864;                        // 67108864 B
  char* wbase = ws + 134217728;
  char* W0b = wbase;                               // 1 MiB
  char* Wh0b = wbase + 1048576;                    // 1 MiB
  char* Wh1b = wbase + 2 * 1048576;                // 1 MiB
  char* WLb = wbase + 3 * 1048576;                 // 16 KiB
  float* invstd3 = (float*)(wbase + 3 * 1048576 + 16384);  // 12 KiB
  float* invstdL = invstd3 + 3 * 1024;

  hipLaunchKernelGGL(k_prep, dim3(1), dim3(1024), 0, stream,
                     bn_gamma, bn_var, bnL_gamma, bnL_var, WL, invstd3, invstdL, WLb);
  hipLaunchKernelGGL(k_binW, dim3(256), dim3(256), 0, stream, W0, W0b, 784);
  hipLaunchKernelGGL(k_binW, dim3(256), dim3(256), 0, stream, Wh, Wh0b, 1024);
  hipLaunchKernelGGL(k_binW, dim3(256), dim3(256), 0, stream, Wh + 1024 * 1024, Wh1b, 1024);
  hipLaunchKernelGGL(k_binX, dim3(16384), dim3(256), 0, stream, x, X0);

  hipLaunchKernelGGL(gemm_bin, dim3(4096), dim3(256), 0, stream, X0, W0b, X1,
                     bn_mean, bn_beta, invstd3);
  hipLaunchKernelGGL(gemm_bin, dim3(4096), dim3(256), 0, stream, X1, Wh0b, X0,
                     bn_mean + 1024, bn_beta + 1024, invstd3 + 1024);
  hipLaunchKernelGGL(gemm_bin, dim3(4096), dim3(256), 0, stream, X0, Wh1b, X1,
                     bn_mean + 2048, bn_beta + 2048, invstd3 + 2048);
  hipLaunchKernelGGL(gemm_fin, dim3(512), dim3(256), 0, stream, X1, WLb, out,
                     bnL_mean, bnL_beta, invstdL);
}

// Round 5
// 283.303 us; speedup vs baseline: 1.7267x; 1.7267x over previous
//
#include <hip/hip_runtime.h>
#include <hip/hip_bf16.h>
#include <stdint.h>

#define EPSF 1e-5f

typedef __attribute__((ext_vector_type(4))) int i32x4;
typedef __attribute__((ext_vector_type(16))) char c8x16;

__device__ __forceinline__ void gld_lds16(const void* g, void* l) {
  __builtin_amdgcn_global_load_lds((const __attribute__((address_space(1))) void*)g,
                                   (__attribute__((address_space(3))) void*)l, 16, 0, 0);
}

// ---------------- prep: binarize weights [1024 x Ksrc] f32 -> i8 [1024][1024], zero-pad ----------------
__global__ void k_binW(const float* __restrict__ src, char* __restrict__ dst, int Ksrc) {
  int t = blockIdx.x * 256 + threadIdx.x;  // 65536 threads, 16 i8 each
  int c = t & 63;
  int n = t >> 6;
  int kc = Ksrc >> 4;  // 49 (784) or 64 (1024)
  c8x16 o;
  if (c < kc) {
    const float* p = src + (size_t)n * Ksrc + c * 16;
#pragma unroll
    for (int e = 0; e < 16; ++e) o[e] = (p[e] >= 0.0f) ? (char)1 : (char)-1;
  } else {
    o = (c8x16)0;
  }
  *(c8x16*)(dst + (size_t)t * 16) = o;
}

// ---------------- input binarize: x [65536 x 784] f32 -> X [65536 x 1024] i8 +-1, pad 0 ----------------
// sign(2x-1) == (x >= 0.5) exactly
__global__ void k_binX(const float* __restrict__ x, char* __restrict__ X) {
  size_t t = (size_t)blockIdx.x * 256 + threadIdx.x;  // 65536*64 threads
  int c = (int)(t & 63);
  size_t b = t >> 6;
  c8x16 o;
  if (c < 49) {  // 784 = 49*16
    const float* p = x + b * 784 + c * 16;
#pragma unroll
    for (int e = 0; e < 16; ++e) o[e] = (p[e] >= 0.5f) ? (char)1 : (char)-1;
  } else {
    o = (c8x16)0;
  }
  *(c8x16*)(X + b * 1024 + c * 16) = o;
}

// ---------------- small prep: inv_std (exact numpy f32 rounding) + binarized WL [16][1024] i8 ----------------
__global__ void k_prep(const float* __restrict__ bn_gamma, const float* __restrict__ bn_var,
                       const float* __restrict__ bnL_gamma, const float* __restrict__ bnL_var,
                       const float* __restrict__ WL,
                       float* __restrict__ invstd3, float* __restrict__ invstdL,
                       char* __restrict__ WLb) {
  int j = threadIdx.x;  // 1024
#pragma unroll
  for (int i = 0; i < 3; ++i) {
    int idx = i * 1024 + j;
    invstd3[idx] = __fdiv_rn(bn_gamma[idx], __fsqrt_rn(__fadd_rn(bn_var[idx], EPSF)));
  }
  if (j < 10) invstdL[j] = __fdiv_rn(bnL_gamma[j], __fsqrt_rn(__fadd_rn(bnL_var[j], EPSF)));
#pragma unroll
  for (int r = 0; r < 16; ++r) {
    char v = 0;
    if (r < 10) v = (WL[r * 1024 + j] >= 0.0f) ? (char)1 : (char)-1;
    WLb[r * 1024 + j] = v;
  }
}

// ---------------- main fused GEMM: C_bin = binarize(BN(A @ Bt^T)), i8 +-1, 16x16x64 MFMA ----------------
// R2-verified structure, BK=128: 128x128 tile, 4 waves (2x2), 32 MFMA + 16 ds_read_b128 per
// barrier interval per wave, 8 K-iterations. LDS row-major [128][128B], linear dest for
// global_load_lds; global source chunk XOR-pre-swizzled within the 128B row (coalescing kept:
// 8 lanes cover one row contiguously), frag read slot = q ^ (row&7) -> 2-way-only bank aliasing.
// XCD mapping: all 8 bn-blocks of one bm land on the same XCD.
__global__ __launch_bounds__(256, 2)
void gemm_bin(const char* __restrict__ A, const char* __restrict__ Bt,
              char* __restrict__ Cb,
              const float* __restrict__ mean, const float* __restrict__ beta,
              const float* __restrict__ invstd) {
  __shared__ char sA[16384];
  __shared__ char sB[16384];
  const int tid = threadIdx.x;
  const int lane = tid & 63;
  const int wave = tid >> 6;
  const int d = blockIdx.x;  // 0..4095
  const int xcd = d & 7;
  const int idx = d >> 3;
  const int bm = xcd * 64 + (idx >> 3);
  const int bn = idx & 7;
  const int wm = wave >> 1, wn = wave & 1;
  const int l15 = lane & 15, lq = lane >> 4;

  // staging: thread t -> row r*32 + (t>>3), source chunk (t&7)^(row&7) (swizzle within 128B line);
  // LDS dest linear r*4096 + t*16 == row*128 + (t&7)*16
  const int srow = tid >> 3;
  const int schunk = ((tid & 7) ^ (srow & 7)) << 4;
  const char* gA = A + (size_t)(bm * 128 + srow) * 1024 + schunk;
  const char* gB = Bt + (size_t)(bn * 128 + srow) * 1024 + schunk;
  char* lA = sA + (tid & ~63) * 16;
  char* lB = sB + (tid & ~63) * 16;

  i32x4 acc[4][4];
#pragma unroll
  for (int m = 0; m < 4; ++m)
#pragma unroll
    for (int n = 0; n < 4; ++n) acc[m][n] = (i32x4)0;

  for (int k0 = 0; k0 < 1024; k0 += 128) {
#pragma unroll
    for (int r = 0; r < 4; ++r) {
      gld_lds16(gA + k0 + r * 32768, lA + r * 4096);
      gld_lds16(gB + k0 + r * 32768, lB + r * 4096);
    }
    __syncthreads();
#pragma unroll
    for (int s = 0; s < 2; ++s) {
      const int slot = (((s << 2) + lq) ^ (l15 & 7)) << 4;
      i32x4 af[4], bf[4];
#pragma unroll
      for (int m = 0; m < 4; ++m)
        af[m] = *(const i32x4*)(sA + (wm * 64 + m * 16 + l15) * 128 + slot);
#pragma unroll
      for (int n = 0; n < 4; ++n)
        bf[n] = *(const i32x4*)(sB + (wn * 64 + n * 16 + l15) * 128 + slot);
#pragma unroll
      for (int m = 0; m < 4; ++m)
#pragma unroll
        for (int n = 0; n < 4; ++n)
          acc[m][n] = __builtin_amdgcn_mfma_i32_16x16x64_i8(af[m], bf[n], acc[m][n], 0, 0, 0);
    }
    __syncthreads();
  }

  // epilogue: exact int -> f32, BN with np-f32 rounding (no FMA), binarize to i8
  // C/D map (16x16): col = lane&15, row = (lane>>4)*4 + reg
  const int r0 = bm * 128 + wm * 64 + (lq << 2);
  const int c0 = bn * 128 + wn * 64 + l15;
#pragma unroll
  for (int n = 0; n < 4; ++n) {
    const int col = c0 + n * 16;
    const float mu = mean[col], is = invstd[col], be = beta[col];
#pragma unroll
    for (int m = 0; m < 4; ++m) {
#pragma unroll
      for (int j = 0; j < 4; ++j) {
        const int row = r0 + m * 16 + j;
        float y = __fadd_rn(__fmul_rn(__fsub_rn((float)acc[m][n][j], mu), is), be);
        Cb[(size_t)row * 1024 + col] = (y >= 0.0f) ? (char)1 : (char)-1;
      }
    }
  }
}

// ---------------- final layer: out[65536][10] = BN(A @ WLb^T), fp32 out, i8 inputs ----------------
// (verified in R2 -- unchanged)
__global__ __launch_bounds__(256, 2)
void gemm_fin(const char* __restrict__ A, const char* __restrict__ BtL,
              float* __restrict__ out,
              const float* __restrict__ meanL, const float* __restrict__ betaL,
              const float* __restrict__ invstdL) {
  constexpr int K = 1024;
  __shared__ char sA[128 * 64];
  __shared__ char sB[16 * 64];
  const int tid = threadIdx.x;
  const int lane = tid & 63;
  const int wave = tid >> 6;
  const int bm = blockIdx.x;

  const int sr = tid >> 2;
  const int csrc = ((tid & 3) ^ (sr & 3)) << 4;
  const char* gA = A + (size_t)(bm * 128 + sr) * K + csrc;
  const char* gB = BtL + (size_t)sr * K + csrc;
  char* lA = sA + (tid & ~63) * 16;
  char* lB = sB;

  const int slot = ((lane >> 4) ^ (lane & 3)) << 4;
  const char* rA = sA + (wave * 32 + (lane & 15)) * 64 + slot;
  const char* rB = sB + (lane & 15) * 64 + slot;

  i32x4 acc0 = (i32x4)0, acc1 = (i32x4)0;

  for (int k0 = 0; k0 < K; k0 += 64) {
    gld_lds16(gA, lA);
    gld_lds16(gA + (size_t)64 * K, lA + 4096);
    if (tid < 64) gld_lds16(gB, lB);
    gA += 64;
    gB += 64;
    __syncthreads();
    i32x4 af0 = *(const i32x4*)(rA);
    i32x4 af1 = *(const i32x4*)(rA + 16 * 64);
    i32x4 b0 = *(const i32x4*)(rB);
    acc0 = __builtin_amdgcn_mfma_i32_16x16x64_i8(af0, b0, acc0, 0, 0, 0);
    acc1 = __builtin_amdgcn_mfma_i32_16x16x64_i8(af1, b0, acc1, 0, 0, 0);
    __syncthreads();
  }

  const int col = lane & 15;
  if (col < 10) {
    const float mu = meanL[col], is = invstdL[col], be = betaL[col];
    const int r0 = bm * 128 + wave * 32 + ((lane >> 4) << 2);
#pragma unroll
    for (int m = 0; m < 2; ++m) {
      const i32x4 a = (m == 0) ? acc0 : acc1;
#pragma unroll
      for (int j = 0; j < 4; ++j) {
        const int row = r0 + m * 16 + j;
        out[(size_t)row * 10 + col] = __fadd_rn(__fmul_rn(__fsub_rn((float)a[j], mu), is), be);
      }
    }
  }
}

extern "C" void kernel_launch(void* const* d_in, const int* in_sizes, int n_in,
                              void* d_out, int out_size, void* d_ws, size_t ws_size,
                              hipStream_t stream) {
  const float* x = (const float*)d_in[0];
  const float* W0 = (const float*)d_in[1];
  const float* Wh = (const float*)d_in[2];
  const float* WL = (const float*)d_in[3];
  const float* bn_gamma = (const float*)d_in[4];
  const float* bn_beta = (const float*)d_in[5];
  const float* bn_mean = (const float*)d_in[6];
  const float* bn_var = (const float*)d_in[7];
  const float* bnL_gamma = (const float*)d_in[8];
  const float* bnL_beta = (const float*)d_in[9];
  const float* bnL_mean = (const float*)d_in[10];
  const float* bnL_var = (const float*)d_in[11];
  float* out = (float*)d_out;

  // workspace layout (~140 MB)
  char* ws = (char*)d_ws;
  char* X0 = ws;                                   // 67108864 B
  char* X1 = ws + 67108864;                        // 67108864 B
  char* wbase = ws + 134217728;
  char* W0b = wbase;                               // 1 MiB
  char* Wh0b = wbase + 1048576;                    // 1 MiB
  char* Wh1b = wbase + 2 * 1048576;                // 1 MiB
  char* WLb = wbase + 3 * 1048576;                 // 16 KiB
  float* invstd3 = (float*)(wbase + 3 * 1048576 + 16384);  // 12 KiB
  float* invstdL = invstd3 + 3 * 1024;

  hipLaunchKernelGGL(k_prep, dim3(1), dim3(1024), 0, stream,
                     bn_gamma, bn_var, bnL_gamma, bnL_var, WL, invstd3, invstdL, WLb);
  hipLaunchKernelGGL(k_binW, dim3(256), dim3(256), 0, stream, W0, W0b, 784);
  hipLaunchKernelGGL(k_binW, dim3(256), dim3(256), 0, stream, Wh, Wh0b, 1024);
  hipLaunchKernelGGL(k_binW, dim3(256), dim3(256), 0, stream, Wh + 1024 * 1024, Wh1b, 1024);
  hipLaunchKernelGGL(k_binX, dim3(16384), dim3(256), 0, stream, x, X0);

  hipLaunchKernelGGL(gemm_bin, dim3(4096), dim3(256), 0, stream, X0, W0b, X1,
                     bn_mean, bn_beta, invstd3);
  hipLaunchKernelGGL(gemm_bin, dim3(4096), dim3(256), 0, stream, X1, Wh0b, X0,
                     bn_mean + 1024, bn_beta + 1024, invstd3 + 1024);
  hipLaunchKernelGGL(gemm_bin, dim3(4096), dim3(256), 0, stream, X0, Wh1b, X1,
                     bn_mean + 2048, bn_beta + 2048, invstd3 + 2048);
  hipLaunchKernelGGL(gemm_fin, dim3(512), dim3(256), 0, stream, X1, WLb, out,
                     bnL_mean, bnL_beta, invstdL);
}